// Round 3
// baseline (121.082 us; speedup 1.0000x reference)
//
#include <hip/hip_runtime.h>
#include <math.h>

#define NQ 10
#define DIM 1024
#define NT 256
#define NLAYERS 4
#define NGATES (NLAYERS * NQ)
#define LDSN (DIM + DIM / 16)   // +skew padding: loc(i) = i + (i>>4)

typedef float v2f __attribute__((ext_vector_type(2)));
typedef float v4f __attribute__((ext_vector_type(4)));

__device__ __forceinline__ v2f mk2(float a, float b) { v2f r; r.x = a; r.y = b; return r; }

// packed gate entry m = {u.re, u.re, -u.im, u.im}; complex acc += u*s as 2x v_pk_fma_f32
__device__ __forceinline__ v2f cfma_m(v2f acc, v4f m, v2f s) {
    acc = __builtin_elementwise_fma(m.xy, s, acc);
    acc = __builtin_elementwise_fma(m.zw, s.yx, acc);
    return acc;
}
__device__ __forceinline__ v2f cmul_m(v4f m, v2f s) {
    v2f r = m.xy * s;
    return __builtin_elementwise_fma(m.zw, s.yx, r);
}
// generic complex mul a*b (a,b as {re,im})
__device__ __forceinline__ v2f cmul(v2f a, v2f b) {
    v2f r = a.xx * b;
    return __builtin_elementwise_fma(mk2(-a.y, a.y), b.yx, r);
}
__device__ __forceinline__ v4f pack_u(float re, float im) {
    v4f m; m.x = re; m.y = re; m.z = -im; m.w = im; return m;
}
// (s0,s1) <- U*(s0,s1), U given as 4 packed entries M[0..3]
__device__ __forceinline__ void apply2_m(const v4f* M, v2f& s0, v2f& s1) {
    v2f n0 = cmul_m(M[0], s0); n0 = cfma_m(n0, M[1], s1);
    v2f n1 = cmul_m(M[2], s0); n1 = cfma_m(n1, M[3], s1);
    s0 = n0; s1 = n1;
}

__global__ __launch_bounds__(NT) void qsim_kernel(const float* __restrict__ x,
                                                  const float* __restrict__ w,
                                                  float* __restrict__ out)
{
    __shared__ v2f stA[LDSN];
    __shared__ v2f stB[LDSN];
    __shared__ v4f matsL[NGATES * 4];
    __shared__ v2f encf[NQ][2];
    __shared__ float red[NT / 64][NQ];

    const int t = threadIdx.x;
    const long sample = blockIdx.x;

    // ---- setup: wave 0 lanes 0..39 build variational mats; wave 1 lanes 0..9 enc factors ----
    if (t < NGATES) {
        float w0 = w[t * 3 + 0], w1 = w[t * 3 + 1], w2 = w[t * 3 + 2];
        float hs = 0.5f * (w0 + w2), hd = 0.5f * (w0 - w2), hy = 0.5f * w1;
        float cy, sy, cs, ss, cd, sd;
        sincosf(hy, &sy, &cy);
        sincosf(hs, &ss, &cs);
        sincosf(hd, &sd, &cd);
        // U = RZ(w2) RY(w1) RZ(w0)
        matsL[t * 4 + 0] = pack_u( cy * cs, -cy * ss);
        matsL[t * 4 + 1] = pack_u(-sy * cd, -sy * sd);
        matsL[t * 4 + 2] = pack_u( sy * cd, -sy * sd);
        matsL[t * 4 + 3] = pack_u( cy * cs,  cy * ss);
    }
    if (t >= 64 && t < 64 + NQ) {
        const int q = t - 64;
        const float* xs = x + sample * (2 * NQ);
        float th = 0.7853981633974483f * (xs[q] + 1.0f);       // theta/2
        float ph = 0.7853981633974483f * (xs[NQ + q] + 1.0f);  // phi/2
        float cy, sy, cp, sp;
        sincosf(th, &sy, &cy);
        sincosf(ph, &sp, &cp);
        const float inv = 0.7071067811865476f;
        float a = (cy - sy) * inv, b = (cy + sy) * inv;
        // column 0 of RZ(phi) RY(theta) H  (state is |0>, encoding = product state)
        encf[q][0] = mk2(cp * a, -sp * a);   // u00
        encf[q][1] = mk2(cp * b,  sp * b);   // u10
    }

    // ---- CNOT-ring closed forms for this thread's 4 amps (idx = 4t+k) ----
    int dst1[4], dst5[4];
    #pragma unroll
    for (int k = 0; k < 4; ++k) {
        int xi = 4 * t + k;
        int y = xi; y ^= y >> 1; y ^= y >> 2; y ^= y >> 4; y ^= y >> 8;
        dst1[k] = (y & 0x1FF) | (((y ^ (xi >> 9)) & 1) << 9);
        int lo = xi & 31, hi = (xi >> 5) & 31;
        dst5[k] = (lo << 5) | (lo ^ hi);
    }
    __syncthreads();

    // ---- product-state init (encoding layer folded out) ----
    {
        v2f P = encf[0][(t >> 7) & 1];
        #pragma unroll
        for (int q = 1; q < 8; ++q)
            P = cmul(P, encf[q][(t >> (7 - q)) & 1]);
        v2f A0 = cmul(P, encf[8][0]);
        v2f A1 = cmul(P, encf[8][1]);
        v2f f90 = encf[9][0], f91 = encf[9][1];
        int base = 4 * t + (t >> 2);
        stA[base + 0] = cmul(A0, f90);
        stA[base + 1] = cmul(A0, f91);
        stA[base + 2] = cmul(A1, f90);
        stA[base + 3] = cmul(A1, f91);
    }
    __syncthreads();

    // ---- variational layers; last dgate of each layer scatter-fused with CNOT ring ----
    v2f* cur = stA;
    v2f* nxt = stB;
    #pragma unroll
    for (int l = 0; l < NLAYERS; ++l) {
        #pragma unroll
        for (int j = 0; j < 5; ++j) {
            const int pb = 8 - 2 * j;       // low bit of the pair
            const int m = 1 << pb;
            const v4f* Ma = &matsL[(l * NQ + 2 * j) * 4];  // qubit 2j (bit pb+1)
            const v4f* Mb = Ma + 4;                        // qubit 2j+1 (bit pb)
            int base, str;
            if (pb >= 2) {
                int lo = t & (m - 1), g = t >> pb;
                base = lo + (lo >> 4) + g * (4 * m + ((4 * m) >> 4));
                str = m + (m >> 4);
            } else {
                base = 4 * t + (t >> 2);
                str = 1;
            }
            v2f s00 = cur[base], s01 = cur[base + str];
            v2f s10 = cur[base + 2 * str], s11 = cur[base + 3 * str];
            apply2_m(Mb, s00, s01);
            apply2_m(Mb, s10, s11);
            apply2_m(Ma, s00, s10);
            apply2_m(Ma, s01, s11);
            if (j < 4) {
                cur[base] = s00; cur[base + str] = s01;
                cur[base + 2 * str] = s10; cur[base + 3 * str] = s11;
            } else {
                const int* d = (l & 1) ? dst5 : dst1;
                nxt[d[0] + (d[0] >> 4)] = s00;
                nxt[d[1] + (d[1] >> 4)] = s01;
                nxt[d[2] + (d[2] >> 4)] = s10;
                nxt[d[3] + (d[3] >> 4)] = s11;
            }
            __syncthreads();
        }
        v2f* tmp = cur; cur = nxt; nxt = tmp;
    }

    // ---- measurement ----
    {
        int base = 4 * t + (t >> 2);
        v2f a0 = cur[base + 0], a1 = cur[base + 1], a2 = cur[base + 2], a3 = cur[base + 3];
        float p0 = a0.x * a0.x + a0.y * a0.y;
        float p1 = a1.x * a1.x + a1.y * a1.y;
        float p2 = a2.x * a2.x + a2.y * a2.y;
        float p3 = a3.x * a3.x + a3.y * a3.y;
        float S = p0 + p1 + p2 + p3;
        float acc[NQ];
        #pragma unroll
        for (int q = 0; q < 8; ++q)
            acc[q] = ((t >> (7 - q)) & 1) ? -S : S;
        acc[8] = (p0 + p1) - (p2 + p3);
        acc[9] = (p0 - p1) + (p2 - p3);
        #pragma unroll
        for (int q = 0; q < NQ; ++q) {
            #pragma unroll
            for (int o = 32; o >= 1; o >>= 1)
                acc[q] += __shfl_xor(acc[q], o);
        }
        const int wave = t >> 6, lane = t & 63;
        if (lane == 0) {
            #pragma unroll
            for (int q = 0; q < NQ; ++q) red[wave][q] = acc[q];
        }
        __syncthreads();
        if (t < NQ)
            out[sample * NQ + t] = red[0][t] + red[1][t] + red[2][t] + red[3][t];
    }
}

extern "C" void kernel_launch(void* const* d_in, const int* in_sizes, int n_in,
                              void* d_out, int out_size, void* d_ws, size_t ws_size,
                              hipStream_t stream) {
    const float* x = (const float*)d_in[0];   // (16,256,20) fp32
    const float* w = (const float*)d_in[1];   // (4,10,3)   fp32
    float* out = (float*)d_out;               // (16,256,10) fp32
    const int n_samples = in_sizes[0] / (2 * NQ);  // 4096
    qsim_kernel<<<n_samples, NT, 0, stream>>>(x, w, out);
}

// Round 4
// 82.693 us; speedup vs baseline: 1.4642x; 1.4642x over previous
//
#include <hip/hip_runtime.h>
#include <math.h>

#define NQ 10
#define NLAYERS 4
#define NGATES (NLAYERS * NQ)

typedef float v2f __attribute__((ext_vector_type(2)));
typedef float v4f __attribute__((ext_vector_type(4)));

__device__ __forceinline__ v2f mk2(float a, float b) { v2f r; r.x = a; r.y = b; return r; }

// packed gate entry m = {re, re, -im, im}; complex u*s / acc+u*s as v_pk_fma_f32
__device__ __forceinline__ v2f cmul_m(v4f m, v2f s) {
    v2f r = m.xy * s;
    return __builtin_elementwise_fma(m.zw, s.yx, r);
}
__device__ __forceinline__ v2f cfma_m(v2f acc, v4f m, v2f s) {
    acc = __builtin_elementwise_fma(m.xy, s, acc);
    acc = __builtin_elementwise_fma(m.zw, s.yx, acc);
    return acc;
}
// generic complex mul a*b ({re,im})
__device__ __forceinline__ v2f cmul(v2f a, v2f b) {
    v2f r = a.xx * b;
    return __builtin_elementwise_fma(mk2(-a.y, a.y), b.yx, r);
}
__device__ __forceinline__ v4f pack_u(float re, float im) {
    v4f m; m.x = re; m.y = re; m.z = -im; m.w = im; return m;
}

// CNOT-ring permutations (GF(2)-linear; closed forms verified in R3)
__host__ __device__ constexpr int pxor1(int v) {   // off = 1 (even layers)
    int y = v; y ^= y >> 1; y ^= y >> 2; y ^= y >> 4; y ^= y >> 8;
    return (y & 0x1FF) | (((y ^ (v >> 9)) & 1) << 9);
}
__host__ __device__ constexpr int pxor5(int v) {   // off = 5 (odd layers)
    int lo = v & 31, hi = (v >> 5) & 31;
    return (lo << 5) | (lo ^ hi);
}

// 1-qubit gate on register bit b (all indices constant after unroll)
__device__ __forceinline__ void apply_gate(v2f* st, const v4f* __restrict__ M, int b) {
    v4f m0 = M[0], m1 = M[1], m2 = M[2], m3 = M[3];
    #pragma unroll
    for (int g = 0; g < 16; ++g) {
        int r0 = ((g >> b) << (b + 1)) | (g & ((1 << b) - 1));
        int r1 = r0 | (1 << b);
        v2f s0v = st[r0], s1v = st[r1];
        v2f n0 = cmul_m(m0, s0v); n0 = cfma_m(n0, m1, s1v);
        v2f n1 = cmul_m(m2, s0v); n1 = cfma_m(n1, m3, s1v);
        st[r0] = n0; st[r1] = n1;
    }
}

// contiguous reload: lane L owns 32 consecutive v2f at element 34*L (16B-aligned)
__device__ __forceinline__ void load_contig(v2f* st, const v2f* scratch, int lane) {
    const v4f* rp = (const v4f*)(scratch + 34 * lane);
    #pragma unroll
    for (int k = 0; k < 16; ++k) { v4f t = rp[k]; st[2 * k] = t.xy; st[2 * k + 1] = t.zw; }
}

__global__ void setup_mats(const float* __restrict__ w, v4f* __restrict__ mats) {
    int g = threadIdx.x;
    if (g >= NGATES) return;
    float w0 = w[g * 3 + 0], w1 = w[g * 3 + 1], w2 = w[g * 3 + 2];
    float hs = 0.5f * (w0 + w2), hd = 0.5f * (w0 - w2), hy = 0.5f * w1;
    float cy, sy, cs, ss, cd, sd;
    sincosf(hy, &sy, &cy);
    sincosf(hs, &ss, &cs);
    sincosf(hd, &sd, &cd);
    // U = RZ(w2) RY(w1) RZ(w0)
    mats[g * 4 + 0] = pack_u( cy * cs, -cy * ss);
    mats[g * 4 + 1] = pack_u(-sy * cd, -sy * sd);
    mats[g * 4 + 2] = pack_u( sy * cd, -sy * sd);
    mats[g * 4 + 3] = pack_u( cy * cs,  cy * ss);
}

// Layouts (2 samples/wave; s = lane>>5, sl = lane&31; amp index bits [9:0], qubit q = bit 9-q):
//  A2: reg r = idx[4:0] (qubits 5..9), lane = (s<<5)|idx[9:5]
//  B2: reg r = idx[9:5] (qubits 0..4), lane = (s<<5)|idx[4:0]
//  LDS slot: loc = 34*newlane + newreg  (stride 34: bank floor on writes, 16B-aligned b128 reads)
__global__ __launch_bounds__(64) void qsim_kernel(const float* __restrict__ x,
                                                  const v4f* __restrict__ mats,
                                                  float* __restrict__ out)
{
    __shared__ __align__(16) v2f scratch[2176];
    __shared__ __align__(16) v2f encf[2][NQ][2];

    const int lane = threadIdx.x;
    const int s = lane >> 5, sl = lane & 31;
    const int sample = 2 * blockIdx.x + s;

    // encoding factors: column 0 of RZ(phi) RY(theta) H  (verified R2/R3)
    if (sl < NQ) {
        const float* xs = x + (long)sample * (2 * NQ);
        float th = 0.7853981633974483f * (xs[sl] + 1.0f);
        float ph = 0.7853981633974483f * (xs[NQ + sl] + 1.0f);
        float cy, sy, cp, sp;
        sincosf(th, &sy, &cy);
        sincosf(ph, &sp, &cp);
        const float inv = 0.7071067811865476f;
        float a = (cy - sy) * inv, b = (cy + sy) * inv;
        v4f e; e.x = cp * a; e.y = -sp * a; e.z = cp * b; e.w = sp * b;
        *(v4f*)&encf[s][sl][0] = e;
    }
    __syncthreads();

    // product-state init directly in registers (layout A2)
    v2f st[32];
    {
        v2f P = encf[s][0][(sl >> 4) & 1];
        P = cmul(P, encf[s][1][(sl >> 3) & 1]);
        P = cmul(P, encf[s][2][(sl >> 2) & 1]);
        P = cmul(P, encf[s][3][(sl >> 1) & 1]);
        P = cmul(P, encf[s][4][sl & 1]);
        v4f e5 = *(const v4f*)&encf[s][5][0];
        v4f e6 = *(const v4f*)&encf[s][6][0];
        v4f e7 = *(const v4f*)&encf[s][7][0];
        v4f e8 = *(const v4f*)&encf[s][8][0];
        v4f e9 = *(const v4f*)&encf[s][9][0];
        v2f P5[2] = { cmul(P, e5.xy), cmul(P, e5.zw) };
        v2f t67[4], t89[4];
        t67[0] = cmul(e6.xy, e7.xy); t67[1] = cmul(e6.xy, e7.zw);
        t67[2] = cmul(e6.zw, e7.xy); t67[3] = cmul(e6.zw, e7.zw);
        t89[0] = cmul(e8.xy, e9.xy); t89[1] = cmul(e8.xy, e9.zw);
        t89[2] = cmul(e8.zw, e9.xy); t89[3] = cmul(e8.zw, e9.zw);
        v2f Q[8];
        #pragma unroll
        for (int a2 = 0; a2 < 2; ++a2)
            #pragma unroll
            for (int b2 = 0; b2 < 4; ++b2)
                Q[(a2 << 2) | b2] = cmul(P5[a2], t67[b2]);
        #pragma unroll
        for (int r = 0; r < 32; ++r)
            st[r] = cmul(Q[r >> 2], t89[r & 3]);
    }

    const int jb1 = pxor1(sl), jb5 = pxor5(sl);   // P(idx) = P(r<<5) ^ P(sl)

    #pragma unroll
    for (int l = 0; l < NLAYERS; ++l) {
        // gates on qubits 5..9 in layout A2 (reg bit 9-q)
        #pragma unroll
        for (int q = 5; q <= 9; ++q)
            apply_gate(st, mats + (l * NQ + q) * 4, 9 - q);

        // swap A2 -> B2: write loc = 34*((s<<5)|r) + sl, read contiguous
        __syncthreads();
        {
            v2f* wp = scratch + 1088 * s + sl;
            #pragma unroll
            for (int r = 0; r < 32; ++r) wp[34 * r] = st[r];
        }
        __syncthreads();
        load_contig(st, scratch, lane);

        // gates on qubits 0..4 in layout B2 (reg bit 4-q)
        #pragma unroll
        for (int q = 0; q <= 4; ++q)
            apply_gate(st, mats + (l * NQ + q) * 4, 4 - q);

        // swap B2 -> A2 with CNOT-ring permutation folded into scatter addresses
        __syncthreads();
        #pragma unroll
        for (int r = 0; r < 32; ++r) {
            const int jc = (l & 1) ? pxor5(r << 5) : pxor1(r << 5);  // compile-time
            const int jb = (l & 1) ? jb5 : jb1;
            const int j = jc ^ jb;                 // dst index within sample
            scratch[1088 * s + j + 2 * (j >> 5)] = st[r];   // 34*(j>>5) + (j&31)
        }
        __syncthreads();
        load_contig(st, scratch, lane);
    }

    // ---- measurement (layout A2: reg bit b -> qubit 9-b; lane bit (4-q) -> qubit q) ----
    {
        float p[32];
        #pragma unroll
        for (int r = 0; r < 32; ++r) {
            v2f a = st[r];
            v2f sq = a * a;
            p[r] = sq.x + sq.y;
        }
        float t0 = 0.f, t1 = 0.f, t2 = 0.f, t3 = 0.f, t4 = 0.f;
        float s0a[16], s1a[8], s2a[4], s3a[2];
        #pragma unroll
        for (int k = 0; k < 16; ++k) { s0a[k] = p[2*k] + p[2*k+1]; t0 += p[2*k] - p[2*k+1]; }
        #pragma unroll
        for (int k = 0; k < 8; ++k)  { s1a[k] = s0a[2*k] + s0a[2*k+1]; t1 += s0a[2*k] - s0a[2*k+1]; }
        #pragma unroll
        for (int k = 0; k < 4; ++k)  { s2a[k] = s1a[2*k] + s1a[2*k+1]; t2 += s1a[2*k] - s1a[2*k+1]; }
        #pragma unroll
        for (int k = 0; k < 2; ++k)  { s3a[k] = s2a[2*k] + s2a[2*k+1]; t3 += s2a[2*k] - s2a[2*k+1]; }
        float S = s3a[0] + s3a[1];   t4 = s3a[0] - s3a[1];

        float acc[NQ];
        #pragma unroll
        for (int q = 0; q < 5; ++q)
            acc[q] = ((sl >> (4 - q)) & 1) ? -S : S;
        acc[5] = t4; acc[6] = t3; acc[7] = t2; acc[8] = t1; acc[9] = t0;

        // butterfly over the 5 lane bits (stays within each 32-lane half)
        #pragma unroll
        for (int q = 0; q < NQ; ++q) {
            #pragma unroll
            for (int o = 16; o >= 1; o >>= 1)
                acc[q] += __shfl_xor(acc[q], o);
        }
        float v = acc[0];
        #pragma unroll
        for (int q = 1; q < NQ; ++q) v = (sl == q) ? acc[q] : v;
        if (sl < NQ)
            out[(long)sample * NQ + sl] = v;
    }
}

extern "C" void kernel_launch(void* const* d_in, const int* in_sizes, int n_in,
                              void* d_out, int out_size, void* d_ws, size_t ws_size,
                              hipStream_t stream) {
    const float* x = (const float*)d_in[0];   // (16,256,20) fp32
    const float* w = (const float*)d_in[1];   // (4,10,3)   fp32
    float* out = (float*)d_out;               // (16,256,10) fp32
    v4f* mats = (v4f*)d_ws;                   // 40 gates x 4 packed entries
    const int n_samples = in_sizes[0] / (2 * NQ);  // 4096
    setup_mats<<<1, 64, 0, stream>>>(w, mats);
    qsim_kernel<<<n_samples / 2, 64, 0, stream>>>(x, mats, out);
}

// Round 5
// 78.554 us; speedup vs baseline: 1.5414x; 1.0527x over previous
//
#include <hip/hip_runtime.h>
#include <math.h>

#define NQ 10
#define NLAYERS 4
#define NGATES (NLAYERS * NQ)

typedef float v2f __attribute__((ext_vector_type(2)));
typedef float v4f __attribute__((ext_vector_type(4)));

__device__ __forceinline__ v2f mk2(float a, float b) { v2f r; r.x = a; r.y = b; return r; }

// packed gate entry m = {re, re, -im, im}; complex u*s / acc+u*s as v_pk_fma_f32
__device__ __forceinline__ v2f cmul_m(v4f m, v2f s) {
    v2f r = m.xy * s;
    return __builtin_elementwise_fma(m.zw, s.yx, r);
}
__device__ __forceinline__ v2f cfma_m(v2f acc, v4f m, v2f s) {
    acc = __builtin_elementwise_fma(m.xy, s, acc);
    acc = __builtin_elementwise_fma(m.zw, s.yx, acc);
    return acc;
}
// generic complex mul a*b ({re,im})
__device__ __forceinline__ v2f cmul(v2f a, v2f b) {
    v2f r = a.xx * b;
    return __builtin_elementwise_fma(mk2(-a.y, a.y), b.yx, r);
}
__device__ __forceinline__ v4f pack_u(float re, float im) {
    v4f m; m.x = re; m.y = re; m.z = -im; m.w = im; return m;
}

// CNOT-ring permutations (GF(2)-linear; closed forms verified R3/R4)
__host__ __device__ constexpr int pxor1(int v) {   // off = 1 (even layers)
    int y = v; y ^= y >> 1; y ^= y >> 2; y ^= y >> 4; y ^= y >> 8;
    return (y & 0x1FF) | (((y ^ (v >> 9)) & 1) << 9);
}
__host__ __device__ constexpr int pxor5(int v) {   // off = 5 (odd layers)
    int lo = v & 31, hi = (v >> 5) & 31;
    return (lo << 5) | (lo ^ hi);
}

// 1-qubit gate on register bit b (all indices constant after unroll)
__device__ __forceinline__ void apply_gate(v2f* st, const v4f* __restrict__ M, int b) {
    v4f m0 = M[0], m1 = M[1], m2 = M[2], m3 = M[3];
    #pragma unroll
    for (int g = 0; g < 16; ++g) {
        int r0 = ((g >> b) << (b + 1)) | (g & ((1 << b) - 1));
        int r1 = r0 | (1 << b);
        v2f s0v = st[r0], s1v = st[r1];
        v2f n0 = cmul_m(m0, s0v); n0 = cfma_m(n0, m1, s1v);
        v2f n1 = cmul_m(m2, s0v); n1 = cfma_m(n1, m3, s1v);
        st[r0] = n0; st[r1] = n1;
    }
}

// contiguous reload: lane L owns 32 consecutive v2f at element 34*L (16B-aligned)
__device__ __forceinline__ void load_contig(v2f* st, const v2f* scratch, int lane) {
    const v4f* rp = (const v4f*)(scratch + 34 * lane);
    #pragma unroll
    for (int k = 0; k < 16; ++k) { v4f t = rp[k]; st[2 * k] = t.xy; st[2 * k + 1] = t.zw; }
}

// Layouts (2 samples/wave; s = lane>>5, sl = lane&31; amp idx bits [9:0], qubit q = bit 9-q):
//  A2: reg r = idx[4:0] (qubits 5..9), lane = idx[9:5]
//  B2: reg r = idx[9:5] (qubits 0..4), lane = idx[4:0]
//  LDS slot: loc = 34*newlane + newreg  (stride 34: write bank-floor, 16B-aligned b128 reads)
// Layer 0's rotations are folded into the encoding product factors (product state);
// layer 3's CNOT perm is folded into measurement signs (GF(2)-linear parities).
__global__ __launch_bounds__(64) void qsim_kernel(const float* __restrict__ x,
                                                  const float* __restrict__ w,
                                                  float* __restrict__ out)
{
    __shared__ __align__(16) v2f scratch[2176];
    __shared__ __align__(16) v4f matsL[NGATES * 4];
    __shared__ __align__(16) v2f encf[2][NQ][2];

    const int lane = threadIdx.x;
    const int s = lane >> 5, sl = lane & 31;
    const long sample = 2L * blockIdx.x + s;

    // ---- per-block setup: 40 variational mats (lanes 0..39) ----
    if (lane < NGATES) {
        float w0 = w[lane * 3 + 0], w1 = w[lane * 3 + 1], w2 = w[lane * 3 + 2];
        float hs = 0.5f * (w0 + w2), hd = 0.5f * (w0 - w2), hy = 0.5f * w1;
        float cy, sy, cs, ss, cd, sd;
        sincosf(hy, &sy, &cy);
        sincosf(hs, &ss, &cs);
        sincosf(hd, &sd, &cd);
        // U = RZ(w2) RY(w1) RZ(w0)
        matsL[lane * 4 + 0] = pack_u( cy * cs, -cy * ss);
        matsL[lane * 4 + 1] = pack_u(-sy * cd, -sy * sd);
        matsL[lane * 4 + 2] = pack_u( sy * cd, -sy * sd);
        matsL[lane * 4 + 3] = pack_u( cy * cs,  cy * ss);
    }
    __syncthreads();

    // ---- encoding factors with layer-0 rotations folded: g_q = U_{0,q} * f_q ----
    if (sl < NQ) {
        const float* xs = x + sample * (2 * NQ);
        float th = 0.7853981633974483f * (xs[sl] + 1.0f);
        float ph = 0.7853981633974483f * (xs[NQ + sl] + 1.0f);
        float cy, sy, cp, sp;
        sincosf(th, &sy, &cy);
        sincosf(ph, &sp, &cp);
        const float inv = 0.7071067811865476f;
        float a = (cy - sy) * inv, b = (cy + sy) * inv;
        v2f f0 = mk2(cp * a, -sp * a);   // column 0 of RZ(phi) RY(theta) H
        v2f f1 = mk2(cp * b,  sp * b);
        v4f M0 = matsL[sl * 4 + 0], M1 = matsL[sl * 4 + 1];
        v4f M2 = matsL[sl * 4 + 2], M3 = matsL[sl * 4 + 3];
        encf[s][sl][0] = cfma_m(cmul_m(M0, f0), M1, f1);
        encf[s][sl][1] = cfma_m(cmul_m(M2, f0), M3, f1);
    }
    __syncthreads();

    // ---- product-state init in layout B2 (reg bit k = qubit 4-k, lane bit k = qubit 9-k) ----
    v2f st[32];
    {
        v2f P = encf[s][5][(sl >> 4) & 1];
        P = cmul(P, encf[s][6][(sl >> 3) & 1]);
        P = cmul(P, encf[s][7][(sl >> 2) & 1]);
        P = cmul(P, encf[s][8][(sl >> 1) & 1]);
        P = cmul(P, encf[s][9][sl & 1]);
        v2f q01[4], q23[4], q234[8], Pq[4];
        #pragma unroll
        for (int a2 = 0; a2 < 4; ++a2) {
            q01[a2] = cmul(encf[s][0][(a2 >> 1) & 1], encf[s][1][a2 & 1]);
            q23[a2] = cmul(encf[s][2][(a2 >> 1) & 1], encf[s][3][a2 & 1]);
        }
        #pragma unroll
        for (int b2 = 0; b2 < 8; ++b2)
            q234[b2] = cmul(q23[b2 >> 1], encf[s][4][b2 & 1]);
        #pragma unroll
        for (int a2 = 0; a2 < 4; ++a2) Pq[a2] = cmul(P, q01[a2]);
        #pragma unroll
        for (int r = 0; r < 32; ++r)
            st[r] = cmul(Pq[r >> 3], q234[r & 7]);
    }

    const int jb1 = pxor1(sl), jb5 = pxor5(sl);   // P(idx) = P(r<<5) ^ P(sl)

    // ---- layer 0 = CNOT perm only (rotations folded): scatter B2 -> A2 with pxor1 ----
    #pragma unroll
    for (int r = 0; r < 32; ++r) {
        const int j = pxor1(r << 5) ^ jb1;
        scratch[1088 * s + 34 * (j >> 5) + (j & 31)] = st[r];
    }
    __syncthreads();
    load_contig(st, scratch, lane);

    // ---- layers 1..3 ----
    #pragma unroll
    for (int l = 1; l < NLAYERS; ++l) {
        // gates on qubits 5..9 in A2 (reg bit 9-q)
        #pragma unroll
        for (int q = 5; q <= 9; ++q)
            apply_gate(st, matsL + (l * NQ + q) * 4, 9 - q);

        // swap A2 -> B2
        __syncthreads();
        {
            v2f* wp = scratch + 1088 * s + sl;
            #pragma unroll
            for (int r = 0; r < 32; ++r) wp[34 * r] = st[r];
        }
        __syncthreads();
        load_contig(st, scratch, lane);

        // gates on qubits 0..4 in B2 (reg bit 4-q)
        #pragma unroll
        for (int q = 0; q <= 4; ++q)
            apply_gate(st, matsL + (l * NQ + q) * 4, 4 - q);

        if (l < NLAYERS - 1) {
            // perm-swap B2 -> A2 with CNOT ring folded into scatter addresses
            __syncthreads();
            #pragma unroll
            for (int r = 0; r < 32; ++r) {
                const int jc = (l & 1) ? pxor5(r << 5) : pxor1(r << 5);  // compile-time
                const int j = jc ^ ((l & 1) ? jb5 : jb1);
                scratch[1088 * s + 34 * (j >> 5) + (j & 31)] = st[r];
            }
            __syncthreads();
            load_contig(st, scratch, lane);
        }
    }

    // ---- measurement in B2 with layer-3 perm (pxor5) folded into signs ----
    // true final index j: j[9:5] = sl, j[4:0] = sl ^ r
    {
        float p[32];
        #pragma unroll
        for (int r = 0; r < 32; ++r) {
            v2f a = st[r];
            v2f sq = a * a;
            p[r] = sq.x + sq.y;
        }
        float t0 = 0.f, t1 = 0.f, t2 = 0.f, t3 = 0.f, t4 = 0.f;
        float s0a[16], s1a[8], s2a[4], s3a[2];
        #pragma unroll
        for (int k = 0; k < 16; ++k) { s0a[k] = p[2*k] + p[2*k+1]; t0 += p[2*k] - p[2*k+1]; }
        #pragma unroll
        for (int k = 0; k < 8; ++k)  { s1a[k] = s0a[2*k] + s0a[2*k+1]; t1 += s0a[2*k] - s0a[2*k+1]; }
        #pragma unroll
        for (int k = 0; k < 4; ++k)  { s2a[k] = s1a[2*k] + s1a[2*k+1]; t2 += s1a[2*k] - s1a[2*k+1]; }
        #pragma unroll
        for (int k = 0; k < 2; ++k)  { s3a[k] = s2a[2*k] + s2a[2*k+1]; t3 += s2a[2*k] - s2a[2*k+1]; }
        float S = s3a[0] + s3a[1];   t4 = s3a[0] - s3a[1];

        float acc[NQ];
        // q=0..4: j bit (9-q) = sl bit (4-q)
        #pragma unroll
        for (int q = 0; q < 5; ++q)
            acc[q] = ((sl >> (4 - q)) & 1) ? -S : S;
        // q=5..9: j bit k=9-q = sl_k ^ r_k  ->  lane-sign * reg-tree t_k
        acc[5] = ((sl >> 4) & 1) ? -t4 : t4;
        acc[6] = ((sl >> 3) & 1) ? -t3 : t3;
        acc[7] = ((sl >> 2) & 1) ? -t2 : t2;
        acc[8] = ((sl >> 1) & 1) ? -t1 : t1;
        acc[9] = (sl & 1)        ? -t0 : t0;

        // butterfly over the 5 lane bits (stays within each 32-lane half)
        #pragma unroll
        for (int q = 0; q < NQ; ++q) {
            #pragma unroll
            for (int o = 16; o >= 1; o >>= 1)
                acc[q] += __shfl_xor(acc[q], o);
        }
        float v = acc[0];
        #pragma unroll
        for (int q = 1; q < NQ; ++q) v = (sl == q) ? acc[q] : v;
        if (sl < NQ)
            out[sample * NQ + sl] = v;
    }
}

extern "C" void kernel_launch(void* const* d_in, const int* in_sizes, int n_in,
                              void* d_out, int out_size, void* d_ws, size_t ws_size,
                              hipStream_t stream) {
    const float* x = (const float*)d_in[0];   // (16,256,20) fp32
    const float* w = (const float*)d_in[1];   // (4,10,3)   fp32
    float* out = (float*)d_out;               // (16,256,10) fp32
    const int n_samples = in_sizes[0] / (2 * NQ);  // 4096
    qsim_kernel<<<n_samples / 2, 64, 0, stream>>>(x, w, out);
}